// Round 1
// baseline (4513.395 us; speedup 1.0000x reference)
//
#include <hip/hip_runtime.h>
#include <math.h>

#define BB 2
#define TT 2048
#define CC 1024
#define HH 16
#define LL 6
#define VV 32000
#define DD 64
#define FFF 4096
#define MM (BB*TT)   // 4096 tokens

typedef __bf16 bf16;
typedef __bf16 bf16x8 __attribute__((ext_vector_type(8)));
typedef __bf16 bf16x4 __attribute__((ext_vector_type(4)));
typedef float  floatx4 __attribute__((ext_vector_type(4)));

__device__ __forceinline__ void async_copy16(const void* g, void* l) {
    __builtin_amdgcn_global_load_lds(
        (const __attribute__((address_space(1))) void*)g,
        (__attribute__((address_space(3))) void*)l, 16, 0, 0);
}

// ---------------------------------------------------------------------------
// GEMM: out = A @ B^T (+ epilogue). A:[MxK] lda, Bt:[NxK] ldb, bf16 in, fp32 acc.
// MODE 0: bf16 out = acc + bias[n]                  (QKV fused projection)
// MODE 1: bf16 out = acc * scale, z batches over B*H, A/B head-banded (QK^T)
// MODE 2: bf16 out = acc, A=scores z*T*T, Bt=vT z*D*T, out head-banded (PV)
// MODE 3: bf16 out = gelu_exact(acc + bias[n])      (FF1)
// MODE 4: f32  out = acc + bias[n] + res[m*ldo+n]   (o-proj / FF2, in-place x)
// MODE 5: f32  out = acc                            (head)
// ---------------------------------------------------------------------------
template<int BM, int BN, int WM, int WN, int MODE>
__global__ __launch_bounds__(256) void gemm_bt(
    const bf16* __restrict__ A, int lda,
    const bf16* __restrict__ Bt, int ldb,
    int K, void* outp, int ldo,
    const float* __restrict__ bias, const float* res, float scale)
{
    constexpr int MI = WM / 16, NI = WN / 16;
    constexpr int WAVES_N = BN / WN;
    static_assert((BM % 64) == 0 && (BN % 64) == 0, "staging passes");
    static_assert((BM / WM) * (BN / WN) == 4, "4 waves");
    __shared__ __align__(16) bf16 As[BM * 32];
    __shared__ __align__(16) bf16 Bs[BN * 32];

    const int t   = threadIdx.x;
    const int bn0 = blockIdx.x * BN;
    const int bm0 = blockIdx.y * BM;
    const int z   = blockIdx.z;

    if (MODE == 1) {
        size_t ho = (size_t)(z / HH) * TT;
        A  += ho * lda + (z % HH) * DD;
        Bt += ho * ldb + (z % HH) * DD;
    }
    if (MODE == 2) {
        A  += (size_t)z * TT * TT;
        Bt += (size_t)z * DD * TT;
    }

    const int lane = t & 63;
    const int ln   = lane & 15;
    const int quad = lane >> 4;
    const int wave = t >> 6;
    const int wm0  = (wave / WAVES_N) * WM;
    const int wn0  = (wave % WAVES_N) * WN;

    floatx4 acc[MI][NI] = {};

    const int arow = t >> 2;        // 0..63: row within 64-row staging pass
    const int acol = (t & 3) * 8;   // bf16 element offset within 32-wide k-tile

    for (int k0 = 0; k0 < K; k0 += 32) {
#pragma unroll
        for (int p = 0; p < BM / 64; ++p)
            async_copy16(A + (size_t)(bm0 + p * 64 + arow) * lda + k0 + acol,
                         As + p * 2048 + t * 8);
#pragma unroll
        for (int p = 0; p < BN / 64; ++p)
            async_copy16(Bt + (size_t)(bn0 + p * 64 + arow) * ldb + k0 + acol,
                         Bs + p * 2048 + t * 8);
        __syncthreads();   // drains vmcnt: LDS tiles ready
        bf16x8 af[MI], bfv[NI];
#pragma unroll
        for (int i = 0; i < MI; ++i)
            af[i] = *(const bf16x8*)(As + (wm0 + i * 16 + ln) * 32 + quad * 8);
#pragma unroll
        for (int j = 0; j < NI; ++j)
            bfv[j] = *(const bf16x8*)(Bs + (wn0 + j * 16 + ln) * 32 + quad * 8);
#pragma unroll
        for (int i = 0; i < MI; ++i)
#pragma unroll
            for (int j = 0; j < NI; ++j)
                acc[i][j] = __builtin_amdgcn_mfma_f32_16x16x32_bf16(
                    af[i], bfv[j], acc[i][j], 0, 0, 0);
        __syncthreads();   // all reads done before next staging overwrite
    }

#pragma unroll
    for (int i = 0; i < MI; ++i) {
#pragma unroll
        for (int j = 0; j < NI; ++j) {
            const int n = bn0 + wn0 + j * 16 + ln;
            float bv = 0.0f;
            if (MODE == 0 || MODE == 3 || MODE == 4) bv = bias[n];
#pragma unroll
            for (int r = 0; r < 4; ++r) {
                const int m = bm0 + wm0 + i * 16 + quad * 4 + r;
                float v = acc[i][j][r];
                if (MODE == 1) v *= scale;
                if (MODE == 0 || MODE == 3 || MODE == 4) v += bv;
                if (MODE == 3) v = 0.5f * v * (1.0f + erff(v * 0.70710678118654752f));
                if (MODE == 0 || MODE == 3) {
                    ((bf16*)outp)[(size_t)m * ldo + n] = (bf16)v;
                } else if (MODE == 1) {
                    bf16* o = (bf16*)outp + (size_t)z * TT * TT;
                    o[(size_t)m * TT + n] = (bf16)v;
                } else if (MODE == 2) {
                    bf16* o = (bf16*)outp + (size_t)(z / HH) * TT * CC + (size_t)(z % HH) * DD;
                    o[(size_t)m * CC + n] = (bf16)v;
                } else if (MODE == 4) {
                    float* o = (float*)outp;
                    o[(size_t)m * ldo + n] = v + res[(size_t)m * ldo + n];
                } else {
                    ((float*)outp)[(size_t)m * ldo + n] = v;
                }
            }
        }
    }
}

// --------------------- weight transpose + fp32 -> bf16 ---------------------
// in: [z][R][Cc] fp32 -> out: [z][Cc][R] bf16
__global__ void wtrans_kernel(const float* __restrict__ in, bf16* __restrict__ out,
                              int R, int Cc, long long in_bs, long long out_bs)
{
    __shared__ float tile[32][33];
    const float* ip = in  + (size_t)blockIdx.z * in_bs;
    bf16*        op = out + (size_t)blockIdx.z * out_bs;
    int c0 = blockIdx.x * 32, r0 = blockIdx.y * 32;
    int tx = threadIdx.x, ty = threadIdx.y;
#pragma unroll
    for (int r = 0; r < 4; ++r)
        tile[ty + r * 8][tx] = ip[(size_t)(r0 + ty + r * 8) * Cc + c0 + tx];
    __syncthreads();
#pragma unroll
    for (int r = 0; r < 4; ++r)
        op[(size_t)(c0 + ty + r * 8) * R + r0 + tx] = (bf16)tile[tx][ty + r * 8];
}

// transpose V slice of qkv -> vT[z][d][s]   (z = b*H + h)
__global__ void vtrans_kernel(const bf16* __restrict__ qkv, bf16* __restrict__ vT)
{
    __shared__ bf16 tile[32][33];
    int z = blockIdx.z;
    int b = z / HH, h = z % HH;
    int s0 = blockIdx.x * 32, d0 = blockIdx.y * 32;
    int tx = threadIdx.x, ty = threadIdx.y;
    const bf16* in = qkv + (size_t)b * TT * 3 * CC + 2 * CC + h * DD;
#pragma unroll
    for (int r = 0; r < 4; ++r)
        tile[ty + r * 8][tx] = in[(size_t)(s0 + ty + r * 8) * 3 * CC + d0 + tx];
    __syncthreads();
    bf16* o = vT + (size_t)z * DD * TT;
#pragma unroll
    for (int r = 0; r < 4; ++r)
        o[(size_t)(d0 + ty + r * 8) * TT + s0 + tx] = tile[tx][ty + r * 8];
}

__global__ void bias_concat(const float* __restrict__ bq, const float* __restrict__ bk,
                            const float* __restrict__ bv, float* __restrict__ o)
{
    int l = blockIdx.x, c = threadIdx.x;
    o[(size_t)l * 3 * CC + c]          = bq[(size_t)l * CC + c];
    o[(size_t)l * 3 * CC + CC + c]     = bk[(size_t)l * CC + c];
    o[(size_t)l * 3 * CC + 2 * CC + c] = bv[(size_t)l * CC + c];
}

__global__ void embed_kernel(const int* __restrict__ src, const float* __restrict__ semb,
                             const float* __restrict__ pemb, float* __restrict__ x)
{
    int m = blockIdx.x, t = threadIdx.x;
    int tok = src[m];
    int pos = m % TT;
    float4 e = ((const float4*)(semb + (size_t)tok * CC))[t];
    float4 p = ((const float4*)(pemb + (size_t)pos * CC))[t];
    float4 o; o.x = e.x + p.x; o.y = e.y + p.y; o.z = e.z + p.z; o.w = e.w + p.w;
    ((float4*)(x + (size_t)m * CC))[t] = o;
}

// LayerNorm row (C=1024) fp32 -> bf16, 256 threads, float4 per thread
__global__ __launch_bounds__(256) void ln_kernel(
    const float* __restrict__ x, const float* __restrict__ w,
    const float* __restrict__ b, bf16* __restrict__ out)
{
    __shared__ float red[4];
    int row = blockIdx.x, t = threadIdx.x;
    float4 v = ((const float4*)(x + (size_t)row * CC))[t];
    float s = v.x + v.y + v.z + v.w;
    for (int off = 32; off; off >>= 1) s += __shfl_xor(s, off, 64);
    if ((t & 63) == 0) red[t >> 6] = s;
    __syncthreads();
    s = red[0] + red[1] + red[2] + red[3];
    float mean = s * (1.0f / CC);
    float dx = v.x - mean, dy = v.y - mean, dz = v.z - mean, dw = v.w - mean;
    float q = dx * dx + dy * dy + dz * dz + dw * dw;
    __syncthreads();
    for (int off = 32; off; off >>= 1) q += __shfl_xor(q, off, 64);
    if ((t & 63) == 0) red[t >> 6] = q;
    __syncthreads();
    q = red[0] + red[1] + red[2] + red[3];
    float rstd = rsqrtf(q * (1.0f / CC) + 1e-5f);
    float4 wv = ((const float4*)w)[t];
    float4 bv = ((const float4*)b)[t];
    bf16x4 ov;
    ov[0] = (bf16)(dx * rstd * wv.x + bv.x);
    ov[1] = (bf16)(dy * rstd * wv.y + bv.y);
    ov[2] = (bf16)(dz * rstd * wv.z + bv.z);
    ov[3] = (bf16)(dw * rstd * wv.w + bv.w);
    *(bf16x4*)(out + (size_t)row * CC + t * 4) = ov;
}

// softmax over rows of 2048, bf16 in-place
__global__ __launch_bounds__(256) void softmax_kernel(bf16* __restrict__ scores)
{
    __shared__ float red[4];
    bf16* p = scores + (size_t)blockIdx.x * TT;
    int t = threadIdx.x;
    bf16x8 v8 = *(bf16x8*)(p + t * 8);
    float v[8];
    float mx = -1e30f;
#pragma unroll
    for (int i = 0; i < 8; ++i) { v[i] = (float)v8[i]; mx = fmaxf(mx, v[i]); }
    for (int off = 32; off; off >>= 1) mx = fmaxf(mx, __shfl_xor(mx, off, 64));
    if ((t & 63) == 0) red[t >> 6] = mx;
    __syncthreads();
    mx = fmaxf(fmaxf(red[0], red[1]), fmaxf(red[2], red[3]));
    float s = 0.0f;
#pragma unroll
    for (int i = 0; i < 8; ++i) { v[i] = __expf(v[i] - mx); s += v[i]; }
    __syncthreads();
    for (int off = 32; off; off >>= 1) s += __shfl_xor(s, off, 64);
    if ((t & 63) == 0) red[t >> 6] = s;
    __syncthreads();
    s = red[0] + red[1] + red[2] + red[3];
    float inv = 1.0f / s;
#pragma unroll
    for (int i = 0; i < 8; ++i) v8[i] = (bf16)(v[i] * inv);
    *(bf16x8*)(p + t * 8) = v8;
}

// ---------------------------------------------------------------------------
extern "C" void kernel_launch(void* const* d_in, const int* in_sizes, int n_in,
                              void* d_out, int out_size, void* d_ws, size_t ws_size,
                              hipStream_t stream)
{
    const int*   src     = (const int*)  d_in[0];
    const float* src_emb = (const float*)d_in[1];
    const float* pos_emb = (const float*)d_in[2];
    const float* ln1_w   = (const float*)d_in[3];
    const float* ln1_b   = (const float*)d_in[4];
    const float* wq      = (const float*)d_in[5];
    const float* bq      = (const float*)d_in[6];
    const float* wk      = (const float*)d_in[7];
    const float* bk      = (const float*)d_in[8];
    const float* wv      = (const float*)d_in[9];
    const float* bv      = (const float*)d_in[10];
    const float* wo      = (const float*)d_in[11];
    const float* bo      = (const float*)d_in[12];
    const float* ln2_w   = (const float*)d_in[13];
    const float* ln2_b   = (const float*)d_in[14];
    const float* w1      = (const float*)d_in[15];
    const float* b1      = (const float*)d_in[16];
    const float* w2      = (const float*)d_in[17];
    const float* b2      = (const float*)d_in[18];
    const float* lnf_w   = (const float*)d_in[19];
    const float* lnf_b   = (const float*)d_in[20];
    const float* head_w  = (const float*)d_in[21];

    // --- scratch carved out of d_out (dead before head GEMM overwrites all) ---
    char* ob = (char*)d_out;
    bf16* wqkvT  = (bf16*)(ob);                  // L*3C*C        37,748,736 B
    bf16* woT    = (bf16*)(ob +  37748736);      // L*C*C         12,582,912 B
    bf16* w1T    = (bf16*)(ob +  50331648);      // L*FF*C        50,331,648 B
    bf16* w2T    = (bf16*)(ob + 100663296);      // L*C*FF        50,331,648 B
    bf16* scores = (bf16*)(ob + 150994944);      // B*H*T*T      268,435,456 B
    bf16* ff     = (bf16*)(ob + 419430400);      // M*FF          33,554,432 B
    bf16* qkv    = (bf16*)(ob + 452984832);      // M*3C          25,165,824 B
    bf16* vT     = (bf16*)(ob + 478150656);      // B*H*D*T        8,388,608 B
    bf16* obuf   = (bf16*)(ob + 486539264);      // M*C            8,388,608 B
    // total 494,927,872 B <= out 524,288,000 B

    // --- persistent-through-head scratch in ws ---
    char* wb = (char*)d_ws;
    bf16*  headT = (bf16*)(wb);                  // V*C           65,536,000 B
    float* x     = (float*)(wb + 65536000);      // M*C fp32      16,777,216 B
    bf16*  h     = (bf16*)(wb + 82313216);       // M*C            8,388,608 B
    float* bqkv  = (float*)(wb + 90701824);      // L*3C              73,728 B
    if (ws_size < 90775552) return;              // insufficient scratch

    dim3 tb(32, 8, 1);
    long long cc = (long long)CC * CC, cf = (long long)CC * FFF;
    wtrans_kernel<<<dim3(32, 32, LL), tb, 0, stream>>>(wq, wqkvT,              CC, CC, cc, 3 * cc);
    wtrans_kernel<<<dim3(32, 32, LL), tb, 0, stream>>>(wk, wqkvT + CC * CC,    CC, CC, cc, 3 * cc);
    wtrans_kernel<<<dim3(32, 32, LL), tb, 0, stream>>>(wv, wqkvT + 2 * CC * CC, CC, CC, cc, 3 * cc);
    wtrans_kernel<<<dim3(32, 32, LL), tb, 0, stream>>>(wo, woT, CC, CC, cc, cc);
    wtrans_kernel<<<dim3(FFF / 32, CC / 32, LL), tb, 0, stream>>>(w1, w1T, CC, FFF, cf, cf);
    wtrans_kernel<<<dim3(CC / 32, FFF / 32, LL), tb, 0, stream>>>(w2, w2T, FFF, CC, cf, cf);
    wtrans_kernel<<<dim3(VV / 32, CC / 32, 1), tb, 0, stream>>>(head_w, headT, CC, VV, 0, 0);
    bias_concat<<<LL, CC, 0, stream>>>(bq, bk, bv, bqkv);
    embed_kernel<<<MM, 256, 0, stream>>>(src, src_emb, pos_emb, x);

    for (int l = 0; l < LL; ++l) {
        ln_kernel<<<MM, 256, 0, stream>>>(x, ln1_w + l * CC, ln1_b + l * CC, h);
        // fused QKV projection: [4096 x 3072] = h @ [wq|wk|wv]
        gemm_bt<128, 128, 64, 64, 0><<<dim3(3 * CC / 128, MM / 128, 1), 256, 0, stream>>>(
            h, CC, wqkvT + (size_t)l * 3 * CC * CC, CC, CC,
            qkv, 3 * CC, bqkv + l * 3 * CC, nullptr, 1.0f);
        vtrans_kernel<<<dim3(TT / 32, DD / 32, BB * HH), tb, 0, stream>>>(qkv, vT);
        // scores = Q @ K^T / 8, batched over B*H
        gemm_bt<128, 128, 64, 64, 1><<<dim3(TT / 128, TT / 128, BB * HH), 256, 0, stream>>>(
            qkv, 3 * CC, qkv + CC, 3 * CC, DD,
            scores, TT, nullptr, nullptr, 0.125f);
        softmax_kernel<<<BB * HH * TT, 256, 0, stream>>>(scores);
        // O = P @ V, batched over B*H  (N = D = 64)
        gemm_bt<128, 64, 32, 64, 2><<<dim3(1, TT / 128, BB * HH), 256, 0, stream>>>(
            scores, TT, vT, TT, TT,
            obuf, CC, nullptr, nullptr, 1.0f);
        // x = x + O @ wo + bo   (in-place residual)
        gemm_bt<128, 128, 64, 64, 4><<<dim3(CC / 128, MM / 128, 1), 256, 0, stream>>>(
            obuf, CC, woT + (size_t)l * CC * CC, CC, CC,
            x, CC, bo + l * CC, x, 1.0f);
        ln_kernel<<<MM, 256, 0, stream>>>(x, ln2_w + l * CC, ln2_b + l * CC, h);
        // ff = gelu(h @ w1 + b1)
        gemm_bt<128, 128, 64, 64, 3><<<dim3(FFF / 128, MM / 128, 1), 256, 0, stream>>>(
            h, CC, w1T + (size_t)l * CC * FFF, CC, CC,
            ff, FFF, b1 + l * FFF, nullptr, 1.0f);
        // x = x + ff @ w2 + b2
        gemm_bt<128, 128, 64, 64, 4><<<dim3(CC / 128, MM / 128, 1), 256, 0, stream>>>(
            ff, FFF, w2T + (size_t)l * CC * FFF, FFF, FFF,
            x, CC, b2 + l * CC, x, 1.0f);
    }
    ln_kernel<<<MM, 256, 0, stream>>>(x, lnf_w, lnf_b, h);
    // logits = h @ head_w   -> overwrites ALL of d_out last
    gemm_bt<128, 128, 64, 64, 5><<<dim3(VV / 128, MM / 128, 1), 256, 0, stream>>>(
        h, CC, headT, CC, CC,
        d_out, VV, nullptr, nullptr, 1.0f);
}